// Round 6
// baseline (376.361 us; speedup 1.0000x reference)
//
#include <hip/hip_runtime.h>

#define N_NODES 100000
#define N_EDGES 1600000
#define FT 128

// ---- workspace layout (bytes) ----------------------------------------------
// h          [0,            51,200,000)   N_NODES*FT*4
// row_start  [51,200,000,   51,600,016)   (N_NODES+1) ints, padded
// cursor     [51,600,016,   52,000,016)   N_NODES ints (counts -> cursors)
// sorted     [52,000,016,   64,800,016)   N_EDGES int2 (col, val_bits)
// bsums      [64,800,016,   64,802,064)   512 ints (block partial sums)
#define OFF_H 0
#define OFF_ROWSTART 51200000
#define OFF_CURSOR 51600016
#define OFF_SORTED 52000016
#define OFF_BSUMS 64800016
#define WS_NEEDED 64802064

#define SCAN_CHUNK 1024
#define SCAN_BLOCKS ((N_NODES + SCAN_CHUNK - 1) / SCAN_CHUNK)  // 98

// ---------------------------------------------------------------------------
// Kernel 1: dense projection  h[n][o] = sum_k x[n][k]*W[k][o] + b[o]
// Register-tiled: block = 32 rows x 128 cols; thread = 4 rows x 4 cols.
// ---------------------------------------------------------------------------
__global__ __launch_bounds__(256) void gemm_bias_kernel(
    const float* __restrict__ x,
    const float* __restrict__ W,
    const float* __restrict__ b,
    float* __restrict__ h) {
  __shared__ float xs[32][FT];  // 16 KB

  const int tid = threadIdx.x;
  const int rbase = blockIdx.x * 32;  // 100000 % 32 == 0 -> no tail

  {
    const float4* xsrc = (const float4*)(x + (size_t)rbase * FT);
    float4* xdst = (float4*)&xs[0][0];
#pragma unroll
    for (int i = 0; i < 4; ++i) xdst[tid + 256 * i] = xsrc[tid + 256 * i];
  }
  __syncthreads();

  const int g = tid >> 5;        // 0..7  (row group)
  const int o = (tid & 31) * 4;  // col base 0..124
  const int r0 = g * 4;          // row base within tile

  float acc[4][4] = {{0.f}};

#pragma unroll 4
  for (int k = 0; k < FT; ++k) {
    const float4 w = *(const float4*)(W + k * FT + o);
#pragma unroll
    for (int i = 0; i < 4; ++i) {
      const float xv = xs[r0 + i][k];  // broadcast within 32-lane group
      acc[i][0] = fmaf(xv, w.x, acc[i][0]);
      acc[i][1] = fmaf(xv, w.y, acc[i][1]);
      acc[i][2] = fmaf(xv, w.z, acc[i][2]);
      acc[i][3] = fmaf(xv, w.w, acc[i][3]);
    }
  }

  const float4 bb = *(const float4*)(b + o);
#pragma unroll
  for (int i = 0; i < 4; ++i) {
    float4 r;
    r.x = acc[i][0] + bb.x;
    r.y = acc[i][1] + bb.y;
    r.z = acc[i][2] + bb.z;
    r.w = acc[i][3] + bb.w;
    *(float4*)(h + (size_t)(rbase + r0 + i) * FT + o) = r;
  }
}

// ---------------------------------------------------------------------------
// Kernel 2: row histogram (counts pre-zeroed by memset). int4 edge reads,
// 4 independent atomics per thread.
// ---------------------------------------------------------------------------
__global__ __launch_bounds__(256) void hist_kernel(
    const int* __restrict__ erows, int* counts) {
  const int i = blockIdx.x * blockDim.x + threadIdx.x;  // i indexes int4
  if (i * 4 >= N_EDGES) return;
  const int4 r = ((const int4*)erows)[i];
  atomicAdd(&counts[r.x], 1);
  atomicAdd(&counts[r.y], 1);
  atomicAdd(&counts[r.z], 1);
  atomicAdd(&counts[r.w], 1);
}

// ---------------------------------------------------------------------------
// Scan phase 1: per-block sums of 1024 counts -> bsums[blockIdx].
// ---------------------------------------------------------------------------
__global__ __launch_bounds__(256) void scan1_kernel(
    const int* __restrict__ counts, int* __restrict__ bsums) {
  __shared__ int red[256];
  const int t = threadIdx.x;
  const int idx4 = blockIdx.x * 256 + t;  // int4 index

  int s = 0;
  if (idx4 * 4 < N_NODES) {
    const int4 c = ((const int4*)counts)[idx4];  // N_NODES % 4 == 0
    s = c.x + c.y + c.z + c.w;
  }
  red[t] = s;
  __syncthreads();
#pragma unroll
  for (int off = 128; off > 0; off >>= 1) {
    if (t < off) red[t] += red[t + off];
    __syncthreads();
  }
  if (t == 0) bsums[blockIdx.x] = red[0];
}

// ---------------------------------------------------------------------------
// Scan phase 2: one tiny block exclusive-scans the block sums in place.
// ---------------------------------------------------------------------------
__global__ __launch_bounds__(128) void scan2_kernel(int* __restrict__ bsums) {
  __shared__ int ps[128];
  const int t = threadIdx.x;
  int v = (t < SCAN_BLOCKS) ? bsums[t] : 0;
  ps[t] = v;
  __syncthreads();
#pragma unroll
  for (int off = 1; off < 128; off <<= 1) {
    const int u = (t >= off) ? ps[t - off] : 0;
    __syncthreads();
    ps[t] += u;
    __syncthreads();
  }
  if (t < SCAN_BLOCKS) bsums[t] = (t == 0) ? 0 : ps[t - 1];
}

// ---------------------------------------------------------------------------
// Scan phase 3: block-local exclusive scan + block offset -> row_start, cursor.
// ---------------------------------------------------------------------------
__global__ __launch_bounds__(256) void scan3_kernel(
    const int* __restrict__ counts,
    const int* __restrict__ bsums,
    int* __restrict__ row_start,
    int* __restrict__ cursor) {
  __shared__ int ts[256];
  const int t = threadIdx.x;
  const int idx4 = blockIdx.x * 256 + t;
  const int base = idx4 * 4;

  int4 c = {0, 0, 0, 0};
  if (base < N_NODES) c = ((const int4*)counts)[idx4];  // N_NODES % 4 == 0
  const int s = c.x + c.y + c.z + c.w;
  ts[t] = s;
  __syncthreads();
#pragma unroll
  for (int off = 1; off < 256; off <<= 1) {
    const int u = (t >= off) ? ts[t - off] : 0;
    __syncthreads();
    ts[t] += u;
    __syncthreads();
  }

  if (base < N_NODES) {
    int run = bsums[blockIdx.x] + ((t == 0) ? 0 : ts[t - 1]);
    int4 rs, cu;
    rs.x = run; cu.x = run; run += c.x;
    rs.y = run; cu.y = run; run += c.y;
    rs.z = run; cu.z = run; run += c.z;
    rs.w = run; cu.w = run; run += c.w;
    ((int4*)row_start)[idx4] = rs;
    ((int4*)cursor)[idx4] = cu;
  }
  if (blockIdx.x == 0 && t == 0) row_start[N_NODES] = N_EDGES;
}

// ---------------------------------------------------------------------------
// Kernel 4: scatter edges into CSR order. 4 edges per thread: coalesced
// int4/float4 reads, 4 INDEPENDENT atomics in flight (ILP), then 4 packed
// 8B writes. Attacks the per-edge dependent atomic-return latency chain.
// ---------------------------------------------------------------------------
__global__ __launch_bounds__(256) void scatter_sort_kernel(
    const int* __restrict__ erows,
    const int* __restrict__ ecols,
    const float* __restrict__ evals,
    int* cursor,
    int2* __restrict__ sorted) {
  const int i = blockIdx.x * blockDim.x + threadIdx.x;  // int4 group index
  if (i * 4 >= N_EDGES) return;  // N_EDGES % 4 == 0 -> full groups
  const int4 r = ((const int4*)erows)[i];
  const int4 c = ((const int4*)ecols)[i];
  const float4 v = ((const float4*)evals)[i];

  const int p0 = atomicAdd(&cursor[r.x], 1);
  const int p1 = atomicAdd(&cursor[r.y], 1);
  const int p2 = atomicAdd(&cursor[r.z], 1);
  const int p3 = atomicAdd(&cursor[r.w], 1);

  int2 s0; s0.x = c.x; s0.y = __float_as_int(v.x);
  int2 s1; s1.x = c.y; s1.y = __float_as_int(v.y);
  int2 s2; s2.x = c.z; s2.y = __float_as_int(v.z);
  int2 s3; s3.x = c.w; s3.y = __float_as_int(v.w);
  sorted[p0] = s0;
  sorted[p1] = s1;
  sorted[p2] = s2;
  sorted[p3] = s3;
}

// ---------------------------------------------------------------------------
// Kernel 5: CSR SpMM + fused ReLU. One 32-lane group per output row.
// ---------------------------------------------------------------------------
__global__ __launch_bounds__(256) void spmm_csr_kernel(
    const int* __restrict__ row_start,
    const int2* __restrict__ sorted,
    const float* __restrict__ h,
    float* __restrict__ out) {
  const int tid = threadIdx.x;
  const int row = blockIdx.x * 8 + (tid >> 5);
  if (row >= N_NODES) return;

  const int beg = row_start[row];
  const int end = row_start[row + 1];
  const int j = (tid & 31) * 4;

  float a0 = 0.f, a1 = 0.f, a2 = 0.f, a3 = 0.f;

  int e = beg;
  for (; e + 1 < end; e += 2) {
    const int2 p0 = sorted[e];
    const int2 p1 = sorted[e + 1];
    const float v0 = __int_as_float(p0.y);
    const float v1 = __int_as_float(p1.y);
    const float4 h0 = *(const float4*)(h + (size_t)p0.x * FT + j);
    const float4 h1 = *(const float4*)(h + (size_t)p1.x * FT + j);
    a0 = fmaf(v0, h0.x, a0); a0 = fmaf(v1, h1.x, a0);
    a1 = fmaf(v0, h0.y, a1); a1 = fmaf(v1, h1.y, a1);
    a2 = fmaf(v0, h0.z, a2); a2 = fmaf(v1, h1.z, a2);
    a3 = fmaf(v0, h0.w, a3); a3 = fmaf(v1, h1.w, a3);
  }
  if (e < end) {
    const int2 p0 = sorted[e];
    const float v0 = __int_as_float(p0.y);
    const float4 h0 = *(const float4*)(h + (size_t)p0.x * FT + j);
    a0 = fmaf(v0, h0.x, a0);
    a1 = fmaf(v0, h0.y, a1);
    a2 = fmaf(v0, h0.z, a2);
    a3 = fmaf(v0, h0.w, a3);
  }

  float4 r;
  r.x = fmaxf(a0, 0.f);
  r.y = fmaxf(a1, 0.f);
  r.z = fmaxf(a2, 0.f);
  r.w = fmaxf(a3, 0.f);
  *(float4*)(out + (size_t)row * FT + j) = r;
}

// ---------------------------------------------------------------------------
// Fallback (small ws): atomic scatter + relu.
// ---------------------------------------------------------------------------
__global__ __launch_bounds__(256) void edge_scatter_kernel(
    const int* __restrict__ erows,
    const int* __restrict__ ecols,
    const float* __restrict__ evals,
    const float* __restrict__ h,
    float* out) {
  const int tid = threadIdx.x;
  const int e = blockIdx.x * 8 + (tid >> 5);
  if (e >= N_EDGES) return;
  const int r = erows[e];
  const int c = ecols[e];
  const float v = evals[e];
  const int j = (tid & 31) * 4;
  const float4 hv = *(const float4*)(h + (size_t)c * FT + j);
  float* op = out + (size_t)r * FT + j;
  atomicAdd(op + 0, v * hv.x);
  atomicAdd(op + 1, v * hv.y);
  atomicAdd(op + 2, v * hv.z);
  atomicAdd(op + 3, v * hv.w);
}

__global__ __launch_bounds__(256) void relu_kernel(float* out, int n4) {
  const int i = blockIdx.x * blockDim.x + threadIdx.x;
  if (i < n4) {
    float4 v = ((float4*)out)[i];
    v.x = fmaxf(v.x, 0.f);
    v.y = fmaxf(v.y, 0.f);
    v.z = fmaxf(v.z, 0.f);
    v.w = fmaxf(v.w, 0.f);
    ((float4*)out)[i] = v;
  }
}

extern "C" void kernel_launch(void* const* d_in, const int* in_sizes, int n_in,
                              void* d_out, int out_size, void* d_ws, size_t ws_size,
                              hipStream_t stream) {
  const float* x = (const float*)d_in[0];
  const int* erows = (const int*)d_in[1];
  const int* ecols = (const int*)d_in[2];
  const float* evals = (const float*)d_in[3];
  const float* W = (const float*)d_in[4];
  const float* b = (const float*)d_in[5];
  float* out = (float*)d_out;

  char* ws = (char*)d_ws;
  float* h = (float*)(ws + OFF_H);

  gemm_bias_kernel<<<N_NODES / 32, 256, 0, stream>>>(x, W, b, h);

  if (ws_size >= (size_t)WS_NEEDED) {
    int* row_start = (int*)(ws + OFF_ROWSTART);
    int* cursor = (int*)(ws + OFF_CURSOR);
    int2* sorted = (int2*)(ws + OFF_SORTED);
    int* bsums = (int*)(ws + OFF_BSUMS);

    hipMemsetAsync(cursor, 0, N_NODES * sizeof(int), stream);
    hist_kernel<<<(N_EDGES / 4 + 255) / 256, 256, 0, stream>>>(erows, cursor);
    scan1_kernel<<<SCAN_BLOCKS, 256, 0, stream>>>(cursor, bsums);
    scan2_kernel<<<1, 128, 0, stream>>>(bsums);
    scan3_kernel<<<SCAN_BLOCKS, 256, 0, stream>>>(cursor, bsums, row_start,
                                                  cursor);
    scatter_sort_kernel<<<(N_EDGES / 4 + 255) / 256, 256, 0, stream>>>(
        erows, ecols, evals, cursor, sorted);
    spmm_csr_kernel<<<(N_NODES + 7) / 8, 256, 0, stream>>>(row_start, sorted,
                                                           h, out);
  } else {
    hipMemsetAsync(d_out, 0, (size_t)out_size * sizeof(float), stream);
    edge_scatter_kernel<<<(N_EDGES + 7) / 8, 256, 0, stream>>>(erows, ecols,
                                                               evals, h, out);
    const int n4 = out_size / 4;
    relu_kernel<<<(n4 + 255) / 256, 256, 0, stream>>>(out, n4);
  }
}

// Round 7
// 277.630 us; speedup vs baseline: 1.3556x; 1.3556x over previous
//
#include <hip/hip_runtime.h>

#define N_NODES 100000
#define N_EDGES 1600000
#define FT 128

// ---- workspace layout (bytes) ----------------------------------------------
// h          [0,            51,200,000)   N_NODES*FT*4
// row_start  [51,200,000,   51,600,016)   (N_NODES+1) ints, padded
// counts     [51,600,016,   58,000,016)   N_NODES ints PADDED stride 16 (64B/row)
// sorted     [58,000,016,   70,800,016)   N_EDGES int2 (col, val_bits)
// rank16     [70,800,016,   74,000,016)   N_EDGES ushort
// bsums      [74,000,016,   74,002,064)   512 ints
#define OFF_H 0
#define OFF_ROWSTART 51200000
#define OFF_COUNTS 51600016
#define OFF_SORTED 58000016
#define OFF_RANK 70800016
#define OFF_BSUMS 74000016
#define WS_NEEDED 74002064

#define CSTRIDE 16  // ints between counters: 1 counter per 64B line

#define SCAN_CHUNK 1024
#define SCAN_BLOCKS ((N_NODES + SCAN_CHUNK - 1) / SCAN_CHUNK)  // 98

// ---------------------------------------------------------------------------
// Kernel 1: dense projection  h = x @ W + b.  Register-tiled 32x128,
// thread = 4x4.
// ---------------------------------------------------------------------------
__global__ __launch_bounds__(256) void gemm_bias_kernel(
    const float* __restrict__ x,
    const float* __restrict__ W,
    const float* __restrict__ b,
    float* __restrict__ h) {
  __shared__ float xs[32][FT];  // 16 KB

  const int tid = threadIdx.x;
  const int rbase = blockIdx.x * 32;

  {
    const float4* xsrc = (const float4*)(x + (size_t)rbase * FT);
    float4* xdst = (float4*)&xs[0][0];
#pragma unroll
    for (int i = 0; i < 4; ++i) xdst[tid + 256 * i] = xsrc[tid + 256 * i];
  }
  __syncthreads();

  const int g = tid >> 5;
  const int o = (tid & 31) * 4;
  const int r0 = g * 4;

  float acc[4][4] = {{0.f}};

#pragma unroll 4
  for (int k = 0; k < FT; ++k) {
    const float4 w = *(const float4*)(W + k * FT + o);
#pragma unroll
    for (int i = 0; i < 4; ++i) {
      const float xv = xs[r0 + i][k];
      acc[i][0] = fmaf(xv, w.x, acc[i][0]);
      acc[i][1] = fmaf(xv, w.y, acc[i][1]);
      acc[i][2] = fmaf(xv, w.z, acc[i][2]);
      acc[i][3] = fmaf(xv, w.w, acc[i][3]);
    }
  }

  const float4 bb = *(const float4*)(b + o);
#pragma unroll
  for (int i = 0; i < 4; ++i) {
    float4 r;
    r.x = acc[i][0] + bb.x;
    r.y = acc[i][1] + bb.y;
    r.z = acc[i][2] + bb.z;
    r.w = acc[i][3] + bb.w;
    *(float4*)(h + (size_t)(rbase + r0 + i) * FT + o) = r;
  }
}

// ---------------------------------------------------------------------------
// Kernel 2: fused histogram + rank. The atomic return value IS the edge's
// rank within its row; stored coalesced as ushort4. Counters padded to one
// 64B line each to maximize line-level RMW parallelism.
// ---------------------------------------------------------------------------
__global__ __launch_bounds__(256) void hist_rank_kernel(
    const int* __restrict__ erows,
    int* counts,                       // padded, stride CSTRIDE, pre-zeroed
    ushort* __restrict__ rank) {
  const int i = blockIdx.x * blockDim.x + threadIdx.x;  // int4 group
  if (i * 4 >= N_EDGES) return;  // N_EDGES % 4 == 0
  const int4 r = ((const int4*)erows)[i];
  ushort4 rk;
  rk.x = (ushort)atomicAdd(&counts[(size_t)r.x * CSTRIDE], 1);
  rk.y = (ushort)atomicAdd(&counts[(size_t)r.y * CSTRIDE], 1);
  rk.z = (ushort)atomicAdd(&counts[(size_t)r.z * CSTRIDE], 1);
  rk.w = (ushort)atomicAdd(&counts[(size_t)r.w * CSTRIDE], 1);
  ((ushort4*)rank)[i] = rk;
}

// ---------------------------------------------------------------------------
// Scan phase 1: per-block sums of 1024 (padded) counters -> bsums.
// ---------------------------------------------------------------------------
__global__ __launch_bounds__(256) void scan1_kernel(
    const int* __restrict__ counts, int* __restrict__ bsums) {
  __shared__ int red[256];
  const int t = threadIdx.x;
  const int base = blockIdx.x * SCAN_CHUNK + t * 4;

  int s = 0;
#pragma unroll
  for (int j = 0; j < 4; ++j) {
    const int idx = base + j;
    if (idx < N_NODES) s += counts[(size_t)idx * CSTRIDE];
  }
  red[t] = s;
  __syncthreads();
#pragma unroll
  for (int off = 128; off > 0; off >>= 1) {
    if (t < off) red[t] += red[t + off];
    __syncthreads();
  }
  if (t == 0) bsums[blockIdx.x] = red[0];
}

// ---------------------------------------------------------------------------
// Scan phase 2: one tiny block exclusive-scans the 98 block sums in place.
// ---------------------------------------------------------------------------
__global__ __launch_bounds__(128) void scan2_kernel(int* __restrict__ bsums) {
  __shared__ int ps[128];
  const int t = threadIdx.x;
  int v = (t < SCAN_BLOCKS) ? bsums[t] : 0;
  ps[t] = v;
  __syncthreads();
#pragma unroll
  for (int off = 1; off < 128; off <<= 1) {
    const int u = (t >= off) ? ps[t - off] : 0;
    __syncthreads();
    ps[t] += u;
    __syncthreads();
  }
  if (t < SCAN_BLOCKS) bsums[t] = (t == 0) ? 0 : ps[t - 1];
}

// ---------------------------------------------------------------------------
// Scan phase 3: block-local exclusive scan + block offset -> row_start only.
// ---------------------------------------------------------------------------
__global__ __launch_bounds__(256) void scan3_kernel(
    const int* __restrict__ counts,
    const int* __restrict__ bsums,
    int* __restrict__ row_start) {
  __shared__ int ts[256];
  const int t = threadIdx.x;
  const int base = blockIdx.x * SCAN_CHUNK + t * 4;

  int c[4];
  int s = 0;
#pragma unroll
  for (int j = 0; j < 4; ++j) {
    const int idx = base + j;
    c[j] = (idx < N_NODES) ? counts[(size_t)idx * CSTRIDE] : 0;
    s += c[j];
  }
  ts[t] = s;
  __syncthreads();
#pragma unroll
  for (int off = 1; off < 256; off <<= 1) {
    const int u = (t >= off) ? ts[t - off] : 0;
    __syncthreads();
    ts[t] += u;
    __syncthreads();
  }

  if (base < N_NODES) {  // N_NODES % 4 == 0 -> full int4 in range
    int run = bsums[blockIdx.x] + ((t == 0) ? 0 : ts[t - 1]);
    int4 rs;
    rs.x = run; run += c[0];
    rs.y = run; run += c[1];
    rs.z = run; run += c[2];
    rs.w = run; run += c[3];
    ((int4*)row_start)[base >> 2] = rs;
  }
  if (blockIdx.x == 0 && t == 0) row_start[N_NODES] = N_EDGES;
}

// ---------------------------------------------------------------------------
// Kernel 4: atomic-free scatter. pos = row_start[row] + rank; all reads
// coalesced, one scattered 8B store per edge, no dependent atomics.
// ---------------------------------------------------------------------------
__global__ __launch_bounds__(256) void scatter_rank_kernel(
    const int* __restrict__ erows,
    const int* __restrict__ ecols,
    const float* __restrict__ evals,
    const ushort* __restrict__ rank,
    const int* __restrict__ row_start,
    int2* __restrict__ sorted) {
  const int i = blockIdx.x * blockDim.x + threadIdx.x;  // int4 group
  if (i * 4 >= N_EDGES) return;
  const int4 r = ((const int4*)erows)[i];
  const int4 c = ((const int4*)ecols)[i];
  const float4 v = ((const float4*)evals)[i];
  const ushort4 rk = ((const ushort4*)rank)[i];

  const int p0 = row_start[r.x] + rk.x;
  const int p1 = row_start[r.y] + rk.y;
  const int p2 = row_start[r.z] + rk.z;
  const int p3 = row_start[r.w] + rk.w;

  int2 s0; s0.x = c.x; s0.y = __float_as_int(v.x);
  int2 s1; s1.x = c.y; s1.y = __float_as_int(v.y);
  int2 s2; s2.x = c.z; s2.y = __float_as_int(v.z);
  int2 s3; s3.x = c.w; s3.y = __float_as_int(v.w);
  sorted[p0] = s0;
  sorted[p1] = s1;
  sorted[p2] = s2;
  sorted[p3] = s3;
}

// ---------------------------------------------------------------------------
// Kernel 5: CSR SpMM + fused ReLU. One 32-lane group per output row.
// ---------------------------------------------------------------------------
__global__ __launch_bounds__(256) void spmm_csr_kernel(
    const int* __restrict__ row_start,
    const int2* __restrict__ sorted,
    const float* __restrict__ h,
    float* __restrict__ out) {
  const int tid = threadIdx.x;
  const int row = blockIdx.x * 8 + (tid >> 5);
  if (row >= N_NODES) return;

  const int beg = row_start[row];
  const int end = row_start[row + 1];
  const int j = (tid & 31) * 4;

  float a0 = 0.f, a1 = 0.f, a2 = 0.f, a3 = 0.f;

  int e = beg;
  for (; e + 1 < end; e += 2) {
    const int2 p0 = sorted[e];
    const int2 p1 = sorted[e + 1];
    const float v0 = __int_as_float(p0.y);
    const float v1 = __int_as_float(p1.y);
    const float4 h0 = *(const float4*)(h + (size_t)p0.x * FT + j);
    const float4 h1 = *(const float4*)(h + (size_t)p1.x * FT + j);
    a0 = fmaf(v0, h0.x, a0); a0 = fmaf(v1, h1.x, a0);
    a1 = fmaf(v0, h0.y, a1); a1 = fmaf(v1, h1.y, a1);
    a2 = fmaf(v0, h0.z, a2); a2 = fmaf(v1, h1.z, a2);
    a3 = fmaf(v0, h0.w, a3); a3 = fmaf(v1, h1.w, a3);
  }
  if (e < end) {
    const int2 p0 = sorted[e];
    const float v0 = __int_as_float(p0.y);
    const float4 h0 = *(const float4*)(h + (size_t)p0.x * FT + j);
    a0 = fmaf(v0, h0.x, a0);
    a1 = fmaf(v0, h0.y, a1);
    a2 = fmaf(v0, h0.z, a2);
    a3 = fmaf(v0, h0.w, a3);
  }

  float4 r;
  r.x = fmaxf(a0, 0.f);
  r.y = fmaxf(a1, 0.f);
  r.z = fmaxf(a2, 0.f);
  r.w = fmaxf(a3, 0.f);
  *(float4*)(out + (size_t)row * FT + j) = r;
}

// ---------------------------------------------------------------------------
// Fallback (small ws): atomic scatter + relu.
// ---------------------------------------------------------------------------
__global__ __launch_bounds__(256) void edge_scatter_kernel(
    const int* __restrict__ erows,
    const int* __restrict__ ecols,
    const float* __restrict__ evals,
    const float* __restrict__ h,
    float* out) {
  const int tid = threadIdx.x;
  const int e = blockIdx.x * 8 + (tid >> 5);
  if (e >= N_EDGES) return;
  const int r = erows[e];
  const int c = ecols[e];
  const float v = evals[e];
  const int j = (tid & 31) * 4;
  const float4 hv = *(const float4*)(h + (size_t)c * FT + j);
  float* op = out + (size_t)r * FT + j;
  atomicAdd(op + 0, v * hv.x);
  atomicAdd(op + 1, v * hv.y);
  atomicAdd(op + 2, v * hv.z);
  atomicAdd(op + 3, v * hv.w);
}

__global__ __launch_bounds__(256) void relu_kernel(float* out, int n4) {
  const int i = blockIdx.x * blockDim.x + threadIdx.x;
  if (i < n4) {
    float4 v = ((float4*)out)[i];
    v.x = fmaxf(v.x, 0.f);
    v.y = fmaxf(v.y, 0.f);
    v.z = fmaxf(v.z, 0.f);
    v.w = fmaxf(v.w, 0.f);
    ((float4*)out)[i] = v;
  }
}

extern "C" void kernel_launch(void* const* d_in, const int* in_sizes, int n_in,
                              void* d_out, int out_size, void* d_ws, size_t ws_size,
                              hipStream_t stream) {
  const float* x = (const float*)d_in[0];
  const int* erows = (const int*)d_in[1];
  const int* ecols = (const int*)d_in[2];
  const float* evals = (const float*)d_in[3];
  const float* W = (const float*)d_in[4];
  const float* b = (const float*)d_in[5];
  float* out = (float*)d_out;

  char* ws = (char*)d_ws;
  float* h = (float*)(ws + OFF_H);

  gemm_bias_kernel<<<N_NODES / 32, 256, 0, stream>>>(x, W, b, h);

  if (ws_size >= (size_t)WS_NEEDED) {
    int* row_start = (int*)(ws + OFF_ROWSTART);
    int* counts = (int*)(ws + OFF_COUNTS);
    int2* sorted = (int2*)(ws + OFF_SORTED);
    ushort* rank = (ushort*)(ws + OFF_RANK);
    int* bsums = (int*)(ws + OFF_BSUMS);

    hipMemsetAsync(counts, 0, (size_t)N_NODES * CSTRIDE * sizeof(int), stream);
    hist_rank_kernel<<<(N_EDGES / 4 + 255) / 256, 256, 0, stream>>>(
        erows, counts, rank);
    scan1_kernel<<<SCAN_BLOCKS, 256, 0, stream>>>(counts, bsums);
    scan2_kernel<<<1, 128, 0, stream>>>(bsums);
    scan3_kernel<<<SCAN_BLOCKS, 256, 0, stream>>>(counts, bsums, row_start);
    scatter_rank_kernel<<<(N_EDGES / 4 + 255) / 256, 256, 0, stream>>>(
        erows, ecols, evals, rank, row_start, sorted);
    spmm_csr_kernel<<<(N_NODES + 7) / 8, 256, 0, stream>>>(row_start, sorted,
                                                           h, out);
  } else {
    hipMemsetAsync(d_out, 0, (size_t)out_size * sizeof(float), stream);
    edge_scatter_kernel<<<(N_EDGES + 7) / 8, 256, 0, stream>>>(erows, ecols,
                                                               evals, h, out);
    const int n4 = out_size / 4;
    relu_kernel<<<(n4 + 255) / 256, 256, 0, stream>>>(out, n4);
  }
}

// Round 8
// 226.376 us; speedup vs baseline: 1.6625x; 1.2264x over previous
//
#include <hip/hip_runtime.h>

#define N_NODES 100000
#define N_EDGES 1600000
#define FT 128

// ---- workspace layout (bytes) ----------------------------------------------
// h_bf       [0,            25,600,000)   N_NODES*FT*2 (bf16)
// row_start  [25,600,000,   26,000,016)   (N_NODES+1) ints, padded
// counts     [26,000,016,   32,400,016)   N_NODES ints PADDED stride 16 (64B)
// sorted     [32,400,016,   45,200,016)   N_EDGES int2 (col, val_bits)
// rank16     [45,200,016,   48,400,016)   N_EDGES ushort
// bsums      [48,400,016,   48,402,064)   512 ints
#define OFF_H 0
#define OFF_ROWSTART 25600000
#define OFF_COUNTS 26000016
#define OFF_SORTED 32400016
#define OFF_RANK 45200016
#define OFF_BSUMS 48400016
#define WS_NEEDED 48402064

#define CSTRIDE 16  // ints between counters: 1 counter per 64B line

#define SCAN_CHUNK 1024
#define SCAN_BLOCKS ((N_NODES + SCAN_CHUNK - 1) / SCAN_CHUNK)  // 98

// bf16 helpers (RNE pack, shift-unpack) — avoid header API drift.
static __device__ __forceinline__ ushort f2bf(float f) {
  const unsigned u = __float_as_uint(f);
  return (ushort)((u + 0x7FFF + ((u >> 16) & 1)) >> 16);
}
static __device__ __forceinline__ float bf2f(ushort s) {
  return __uint_as_float((unsigned)s << 16);
}

// ---------------------------------------------------------------------------
// Kernel 1: dense projection  h = x @ W + b  (bf16 output).
// Register-tiled 32x128, thread = 4x4.
// ---------------------------------------------------------------------------
__global__ __launch_bounds__(256) void gemm_bias_kernel(
    const float* __restrict__ x,
    const float* __restrict__ W,
    const float* __restrict__ b,
    ushort* __restrict__ h) {
  __shared__ float xs[32][FT];  // 16 KB

  const int tid = threadIdx.x;
  const int rbase = blockIdx.x * 32;

  {
    const float4* xsrc = (const float4*)(x + (size_t)rbase * FT);
    float4* xdst = (float4*)&xs[0][0];
#pragma unroll
    for (int i = 0; i < 4; ++i) xdst[tid + 256 * i] = xsrc[tid + 256 * i];
  }
  __syncthreads();

  const int g = tid >> 5;
  const int o = (tid & 31) * 4;
  const int r0 = g * 4;

  float acc[4][4] = {{0.f}};

#pragma unroll 4
  for (int k = 0; k < FT; ++k) {
    const float4 w = *(const float4*)(W + k * FT + o);
#pragma unroll
    for (int i = 0; i < 4; ++i) {
      const float xv = xs[r0 + i][k];
      acc[i][0] = fmaf(xv, w.x, acc[i][0]);
      acc[i][1] = fmaf(xv, w.y, acc[i][1]);
      acc[i][2] = fmaf(xv, w.z, acc[i][2]);
      acc[i][3] = fmaf(xv, w.w, acc[i][3]);
    }
  }

  const float4 bb = *(const float4*)(b + o);
#pragma unroll
  for (int i = 0; i < 4; ++i) {
    ushort4 r;
    r.x = f2bf(acc[i][0] + bb.x);
    r.y = f2bf(acc[i][1] + bb.y);
    r.z = f2bf(acc[i][2] + bb.z);
    r.w = f2bf(acc[i][3] + bb.w);
    *(ushort4*)(h + (size_t)(rbase + r0 + i) * FT + o) = r;
  }
}

// ---------------------------------------------------------------------------
// Kernel 2: fused histogram + rank (atomic return = rank within row).
// Counters padded to one 64B line each (line-parallel RMWs).
// ---------------------------------------------------------------------------
__global__ __launch_bounds__(256) void hist_rank_kernel(
    const int* __restrict__ erows,
    int* counts,
    ushort* __restrict__ rank) {
  const int i = blockIdx.x * blockDim.x + threadIdx.x;  // int4 group
  if (i * 4 >= N_EDGES) return;  // N_EDGES % 4 == 0
  const int4 r = ((const int4*)erows)[i];
  ushort4 rk;
  rk.x = (ushort)atomicAdd(&counts[(size_t)r.x * CSTRIDE], 1);
  rk.y = (ushort)atomicAdd(&counts[(size_t)r.y * CSTRIDE], 1);
  rk.z = (ushort)atomicAdd(&counts[(size_t)r.z * CSTRIDE], 1);
  rk.w = (ushort)atomicAdd(&counts[(size_t)r.w * CSTRIDE], 1);
  ((ushort4*)rank)[i] = rk;
}

// ---------------------------------------------------------------------------
// Scan phase 1: per-block sums of 1024 (padded) counters -> bsums.
// ---------------------------------------------------------------------------
__global__ __launch_bounds__(256) void scan1_kernel(
    const int* __restrict__ counts, int* __restrict__ bsums) {
  __shared__ int red[256];
  const int t = threadIdx.x;
  const int base = blockIdx.x * SCAN_CHUNK + t * 4;

  int s = 0;
#pragma unroll
  for (int j = 0; j < 4; ++j) {
    const int idx = base + j;
    if (idx < N_NODES) s += counts[(size_t)idx * CSTRIDE];
  }
  red[t] = s;
  __syncthreads();
#pragma unroll
  for (int off = 128; off > 0; off >>= 1) {
    if (t < off) red[t] += red[t + off];
    __syncthreads();
  }
  if (t == 0) bsums[blockIdx.x] = red[0];
}

// ---------------------------------------------------------------------------
// Scan phase 2: one tiny block exclusive-scans the 98 block sums in place.
// ---------------------------------------------------------------------------
__global__ __launch_bounds__(128) void scan2_kernel(int* __restrict__ bsums) {
  __shared__ int ps[128];
  const int t = threadIdx.x;
  int v = (t < SCAN_BLOCKS) ? bsums[t] : 0;
  ps[t] = v;
  __syncthreads();
#pragma unroll
  for (int off = 1; off < 128; off <<= 1) {
    const int u = (t >= off) ? ps[t - off] : 0;
    __syncthreads();
    ps[t] += u;
    __syncthreads();
  }
  if (t < SCAN_BLOCKS) bsums[t] = (t == 0) ? 0 : ps[t - 1];
}

// ---------------------------------------------------------------------------
// Scan phase 3: block-local exclusive scan + block offset -> row_start.
// ---------------------------------------------------------------------------
__global__ __launch_bounds__(256) void scan3_kernel(
    const int* __restrict__ counts,
    const int* __restrict__ bsums,
    int* __restrict__ row_start) {
  __shared__ int ts[256];
  const int t = threadIdx.x;
  const int base = blockIdx.x * SCAN_CHUNK + t * 4;

  int c[4];
  int s = 0;
#pragma unroll
  for (int j = 0; j < 4; ++j) {
    const int idx = base + j;
    c[j] = (idx < N_NODES) ? counts[(size_t)idx * CSTRIDE] : 0;
    s += c[j];
  }
  ts[t] = s;
  __syncthreads();
#pragma unroll
  for (int off = 1; off < 256; off <<= 1) {
    const int u = (t >= off) ? ts[t - off] : 0;
    __syncthreads();
    ts[t] += u;
    __syncthreads();
  }

  if (base < N_NODES) {  // N_NODES % 4 == 0 -> full int4 in range
    int run = bsums[blockIdx.x] + ((t == 0) ? 0 : ts[t - 1]);
    int4 rs;
    rs.x = run; run += c[0];
    rs.y = run; run += c[1];
    rs.z = run; run += c[2];
    rs.w = run; run += c[3];
    ((int4*)row_start)[base >> 2] = rs;
  }
  if (blockIdx.x == 0 && t == 0) row_start[N_NODES] = N_EDGES;
}

// ---------------------------------------------------------------------------
// Kernel 4: atomic-free scatter. pos = row_start[row] + rank.
// ---------------------------------------------------------------------------
__global__ __launch_bounds__(256) void scatter_rank_kernel(
    const int* __restrict__ erows,
    const int* __restrict__ ecols,
    const float* __restrict__ evals,
    const ushort* __restrict__ rank,
    const int* __restrict__ row_start,
    int2* __restrict__ sorted) {
  const int i = blockIdx.x * blockDim.x + threadIdx.x;  // int4 group
  if (i * 4 >= N_EDGES) return;
  const int4 r = ((const int4*)erows)[i];
  const int4 c = ((const int4*)ecols)[i];
  const float4 v = ((const float4*)evals)[i];
  const ushort4 rk = ((const ushort4*)rank)[i];

  const int p0 = row_start[r.x] + rk.x;
  const int p1 = row_start[r.y] + rk.y;
  const int p2 = row_start[r.z] + rk.z;
  const int p3 = row_start[r.w] + rk.w;

  int2 s0; s0.x = c.x; s0.y = __float_as_int(v.x);
  int2 s1; s1.x = c.y; s1.y = __float_as_int(v.y);
  int2 s2; s2.x = c.z; s2.y = __float_as_int(v.z);
  int2 s3; s3.x = c.w; s3.y = __float_as_int(v.w);
  sorted[p0] = s0;
  sorted[p1] = s1;
  sorted[p2] = s2;
  sorted[p3] = s3;
}

// ---------------------------------------------------------------------------
// Kernel 5: CSR SpMM + fused ReLU. One 32-lane group per output row;
// bf16 h gather (8B/lane/edge), 4-edge unroll for load ILP.
// ---------------------------------------------------------------------------
__global__ __launch_bounds__(256) void spmm_csr_kernel(
    const int* __restrict__ row_start,
    const int2* __restrict__ sorted,
    const ushort* __restrict__ h,
    float* __restrict__ out) {
  const int tid = threadIdx.x;
  const int row = blockIdx.x * 8 + (tid >> 5);
  if (row >= N_NODES) return;

  const int beg = row_start[row];
  const int end = row_start[row + 1];
  const int j = (tid & 31) * 4;

  float a0 = 0.f, a1 = 0.f, a2 = 0.f, a3 = 0.f;

  int e = beg;
  for (; e + 3 < end; e += 4) {
    const int2 p0 = sorted[e];
    const int2 p1 = sorted[e + 1];
    const int2 p2 = sorted[e + 2];
    const int2 p3 = sorted[e + 3];
    const ushort4 q0 = *(const ushort4*)(h + (size_t)p0.x * FT + j);
    const ushort4 q1 = *(const ushort4*)(h + (size_t)p1.x * FT + j);
    const ushort4 q2 = *(const ushort4*)(h + (size_t)p2.x * FT + j);
    const ushort4 q3 = *(const ushort4*)(h + (size_t)p3.x * FT + j);
    const float v0 = __int_as_float(p0.y);
    const float v1 = __int_as_float(p1.y);
    const float v2 = __int_as_float(p2.y);
    const float v3 = __int_as_float(p3.y);
    a0 = fmaf(v0, bf2f(q0.x), a0);
    a1 = fmaf(v0, bf2f(q0.y), a1);
    a2 = fmaf(v0, bf2f(q0.z), a2);
    a3 = fmaf(v0, bf2f(q0.w), a3);
    a0 = fmaf(v1, bf2f(q1.x), a0);
    a1 = fmaf(v1, bf2f(q1.y), a1);
    a2 = fmaf(v1, bf2f(q1.z), a2);
    a3 = fmaf(v1, bf2f(q1.w), a3);
    a0 = fmaf(v2, bf2f(q2.x), a0);
    a1 = fmaf(v2, bf2f(q2.y), a1);
    a2 = fmaf(v2, bf2f(q2.z), a2);
    a3 = fmaf(v2, bf2f(q2.w), a3);
    a0 = fmaf(v3, bf2f(q3.x), a0);
    a1 = fmaf(v3, bf2f(q3.y), a1);
    a2 = fmaf(v3, bf2f(q3.z), a2);
    a3 = fmaf(v3, bf2f(q3.w), a3);
  }
  for (; e < end; ++e) {
    const int2 p0 = sorted[e];
    const float v0 = __int_as_float(p0.y);
    const ushort4 q0 = *(const ushort4*)(h + (size_t)p0.x * FT + j);
    a0 = fmaf(v0, bf2f(q0.x), a0);
    a1 = fmaf(v0, bf2f(q0.y), a1);
    a2 = fmaf(v0, bf2f(q0.z), a2);
    a3 = fmaf(v0, bf2f(q0.w), a3);
  }

  float4 r;
  r.x = fmaxf(a0, 0.f);
  r.y = fmaxf(a1, 0.f);
  r.z = fmaxf(a2, 0.f);
  r.w = fmaxf(a3, 0.f);
  *(float4*)(out + (size_t)row * FT + j) = r;
}

// ---------------------------------------------------------------------------
// Fallback (small ws): atomic scatter + relu on bf16 h.
// ---------------------------------------------------------------------------
__global__ __launch_bounds__(256) void edge_scatter_kernel(
    const int* __restrict__ erows,
    const int* __restrict__ ecols,
    const float* __restrict__ evals,
    const ushort* __restrict__ h,
    float* out) {
  const int tid = threadIdx.x;
  const int e = blockIdx.x * 8 + (tid >> 5);
  if (e >= N_EDGES) return;
  const int r = erows[e];
  const int c = ecols[e];
  const float v = evals[e];
  const int j = (tid & 31) * 4;
  const ushort4 q = *(const ushort4*)(h + (size_t)c * FT + j);
  float* op = out + (size_t)r * FT + j;
  atomicAdd(op + 0, v * bf2f(q.x));
  atomicAdd(op + 1, v * bf2f(q.y));
  atomicAdd(op + 2, v * bf2f(q.z));
  atomicAdd(op + 3, v * bf2f(q.w));
}

__global__ __launch_bounds__(256) void relu_kernel(float* out, int n4) {
  const int i = blockIdx.x * blockDim.x + threadIdx.x;
  if (i < n4) {
    float4 v = ((float4*)out)[i];
    v.x = fmaxf(v.x, 0.f);
    v.y = fmaxf(v.y, 0.f);
    v.z = fmaxf(v.z, 0.f);
    v.w = fmaxf(v.w, 0.f);
    ((float4*)out)[i] = v;
  }
}

extern "C" void kernel_launch(void* const* d_in, const int* in_sizes, int n_in,
                              void* d_out, int out_size, void* d_ws, size_t ws_size,
                              hipStream_t stream) {
  const float* x = (const float*)d_in[0];
  const int* erows = (const int*)d_in[1];
  const int* ecols = (const int*)d_in[2];
  const float* evals = (const float*)d_in[3];
  const float* W = (const float*)d_in[4];
  const float* b = (const float*)d_in[5];
  float* out = (float*)d_out;

  char* ws = (char*)d_ws;
  ushort* h = (ushort*)(ws + OFF_H);

  gemm_bias_kernel<<<N_NODES / 32, 256, 0, stream>>>(x, W, b, h);

  if (ws_size >= (size_t)WS_NEEDED) {
    int* row_start = (int*)(ws + OFF_ROWSTART);
    int* counts = (int*)(ws + OFF_COUNTS);
    int2* sorted = (int2*)(ws + OFF_SORTED);
    ushort* rank = (ushort*)(ws + OFF_RANK);
    int* bsums = (int*)(ws + OFF_BSUMS);

    hipMemsetAsync(counts, 0, (size_t)N_NODES * CSTRIDE * sizeof(int), stream);
    hist_rank_kernel<<<(N_EDGES / 4 + 255) / 256, 256, 0, stream>>>(
        erows, counts, rank);
    scan1_kernel<<<SCAN_BLOCKS, 256, 0, stream>>>(counts, bsums);
    scan2_kernel<<<1, 128, 0, stream>>>(bsums);
    scan3_kernel<<<SCAN_BLOCKS, 256, 0, stream>>>(counts, bsums, row_start);
    scatter_rank_kernel<<<(N_EDGES / 4 + 255) / 256, 256, 0, stream>>>(
        erows, ecols, evals, rank, row_start, sorted);
    spmm_csr_kernel<<<(N_NODES + 7) / 8, 256, 0, stream>>>(row_start, sorted,
                                                           h, out);
  } else {
    hipMemsetAsync(d_out, 0, (size_t)out_size * sizeof(float), stream);
    edge_scatter_kernel<<<(N_EDGES + 7) / 8, 256, 0, stream>>>(erows, ecols,
                                                               evals, h, out);
    const int n4 = out_size / 4;
    relu_kernel<<<(n4 + 255) / 256, 256, 0, stream>>>(out, n4);
  }
}

// Round 9
// 195.671 us; speedup vs baseline: 1.9234x; 1.1569x over previous
//
#include <hip/hip_runtime.h>

#define N_NODES 100000
#define N_EDGES 1600000
#define FT 128

// ---- workspace layout (bytes) ----------------------------------------------
// h_bf       [0,            25,600,000)   N_NODES*FT*2 (bf16)
// row_start  [25,600,000,   26,000,016)   (N_NODES+1) ints, padded
// counts     [26,000,016,   32,400,016)   N_NODES ints PADDED stride 16 (64B)
// sorted     [32,400,016,   45,200,016)   N_EDGES int2 (col, val_bits)
// rank16     [45,200,016,   48,400,016)   N_EDGES ushort
// bsums      [48,400,016,   48,402,064)   512 ints
#define OFF_H 0
#define OFF_ROWSTART 25600000
#define OFF_COUNTS 26000016
#define OFF_SORTED 32400016
#define OFF_RANK 45200016
#define OFF_BSUMS 48400016
#define WS_NEEDED 48402064

#define CSTRIDE 16  // ints between counters: 1 counter per 64B line

#define SCAN_CHUNK 1024
#define SCAN_BLOCKS ((N_NODES + SCAN_CHUNK - 1) / SCAN_CHUNK)  // 98

typedef __attribute__((ext_vector_type(8))) short bf16x8;
typedef __attribute__((ext_vector_type(4))) float f32x4;

// bf16 helpers (RNE pack, shift-unpack).
static __device__ __forceinline__ ushort f2bf(float f) {
  const unsigned u = __float_as_uint(f);
  return (ushort)((u + 0x7FFF + ((u >> 16) & 1)) >> 16);
}
static __device__ __forceinline__ float bf2f(ushort s) {
  return __uint_as_float((unsigned)s << 16);
}

// ---------------------------------------------------------------------------
// Kernel 1: dense projection  h = x @ W + b  (bf16 output) via MFMA.
// Block = 256 threads (4 waves); wave = 64 rows x 128 cols.
// W staged in LDS pre-swizzled to 16x16x32 B-fragment order (hi + lo bf16,
// W = W_hi + W_lo keeps W error ~2^-17). x converted to bf16 in-flight.
// A-frag: row=lane&15, k=(lane>>4)*8+i.  B-frag: k=(lane>>4)*8+i, col=lane&15.
// C/D: col=lane&15, row=(lane>>4)*4+reg  [HW-verified mapping].
// ---------------------------------------------------------------------------
__global__ __launch_bounds__(256) void gemm_bias_kernel(
    const float* __restrict__ x,
    const float* __restrict__ W,
    const float* __restrict__ b,
    ushort* __restrict__ h) {
  // fragment-ordered W: [hi/lo][ks(4)][ct(8)][lane(64)][i(8)] ushorts = 32KB ea
  __shared__ __align__(16) ushort whi[16384];
  __shared__ __align__(16) ushort wlo[16384];

  const int tid = threadIdx.x;

  // ---- stage W into LDS in fragment order (one-time, coalesced reads) ----
  for (int idx = tid; idx < 16384; idx += 256) {
    const int k = idx >> 7;
    const int col = idx & 127;
    const float wv = W[idx];
    const ushort hi = f2bf(wv);
    const ushort lo = f2bf(wv - bf2f(hi));
    const int lane_ = (((k >> 3) & 3) << 4) | (col & 15);
    const int pos = ((((k >> 5) << 3) + (col >> 4)) * 64 + lane_) * 8 + (k & 7);
    whi[pos] = hi;
    wlo[pos] = lo;
  }
  __syncthreads();

  const int w = tid >> 6;        // wave 0..3
  const int lane = tid & 63;
  const int r0 = blockIdx.x * 256 + w * 64;  // wave's first row
  const int arow = lane & 15;    // A row within 16-tile
  const int kgrp = (lane >> 4) << 3;  // k sub-offset 0/8/16/24

  // bias per col-tile (col = ct*16 + (lane&15))
  float bias_v[8];
#pragma unroll
  for (int ct = 0; ct < 8; ++ct) bias_v[ct] = b[ct * 16 + (lane & 15)];

  f32x4 acc[4][8];
#pragma unroll
  for (int rf = 0; rf < 4; ++rf)
#pragma unroll
    for (int ct = 0; ct < 8; ++ct) acc[rf][ct] = (f32x4){0.f, 0.f, 0.f, 0.f};

#pragma unroll
  for (int ks = 0; ks < 4; ++ks) {
    // A fragments: 4 row-tiles, bf16 convert in-flight
    bf16x8 afr[4];
#pragma unroll
    for (int rf = 0; rf < 4; ++rf) {
      int r = r0 + rf * 16 + arow;
      r = (r < N_NODES) ? r : (N_NODES - 1);  // clamp tail loads
      const float* xp = x + (size_t)r * FT + ks * 32 + kgrp;
      const float4 u0 = *(const float4*)xp;
      const float4 u1 = *(const float4*)(xp + 4);
      bf16x8 a;
      a[0] = (short)f2bf(u0.x);
      a[1] = (short)f2bf(u0.y);
      a[2] = (short)f2bf(u0.z);
      a[3] = (short)f2bf(u0.w);
      a[4] = (short)f2bf(u1.x);
      a[5] = (short)f2bf(u1.y);
      a[6] = (short)f2bf(u1.z);
      a[7] = (short)f2bf(u1.w);
      afr[rf] = a;
    }
#pragma unroll
    for (int ct = 0; ct < 8; ++ct) {
      const int fo = ((ks * 8 + ct) * 64 + lane) * 8;
      const bf16x8 bh = *(const bf16x8*)&whi[fo];
      const bf16x8 bl = *(const bf16x8*)&wlo[fo];
#pragma unroll
      for (int rf = 0; rf < 4; ++rf) {
        acc[rf][ct] = __builtin_amdgcn_mfma_f32_16x16x32_bf16(
            afr[rf], bh, acc[rf][ct], 0, 0, 0);
        acc[rf][ct] = __builtin_amdgcn_mfma_f32_16x16x32_bf16(
            afr[rf], bl, acc[rf][ct], 0, 0, 0);
      }
    }
  }

  // ---- epilogue: bias + bf16 store via C/D mapping ----
  const int crow0 = (lane >> 4) << 2;  // 0/4/8/12
  const int ccol = lane & 15;
#pragma unroll
  for (int rf = 0; rf < 4; ++rf) {
#pragma unroll
    for (int ct = 0; ct < 8; ++ct) {
      const int col = ct * 16 + ccol;
#pragma unroll
      for (int i = 0; i < 4; ++i) {
        const int row = r0 + rf * 16 + crow0 + i;
        if (row < N_NODES)
          h[(size_t)row * FT + col] = f2bf(acc[rf][ct][i] + bias_v[ct]);
      }
    }
  }
}

// ---------------------------------------------------------------------------
// Kernel 2: fused histogram + rank (atomic return = rank within row).
// Counters padded to one 64B line each (line-parallel RMWs).
// ---------------------------------------------------------------------------
__global__ __launch_bounds__(256) void hist_rank_kernel(
    const int* __restrict__ erows,
    int* counts,
    ushort* __restrict__ rank) {
  const int i = blockIdx.x * blockDim.x + threadIdx.x;  // int4 group
  if (i * 4 >= N_EDGES) return;  // N_EDGES % 4 == 0
  const int4 r = ((const int4*)erows)[i];
  ushort4 rk;
  rk.x = (ushort)atomicAdd(&counts[(size_t)r.x * CSTRIDE], 1);
  rk.y = (ushort)atomicAdd(&counts[(size_t)r.y * CSTRIDE], 1);
  rk.z = (ushort)atomicAdd(&counts[(size_t)r.z * CSTRIDE], 1);
  rk.w = (ushort)atomicAdd(&counts[(size_t)r.w * CSTRIDE], 1);
  ((ushort4*)rank)[i] = rk;
}

// ---------------------------------------------------------------------------
// Scan phase 1: per-block sums of 1024 (padded) counters -> bsums.
// ---------------------------------------------------------------------------
__global__ __launch_bounds__(256) void scan1_kernel(
    const int* __restrict__ counts, int* __restrict__ bsums) {
  __shared__ int red[256];
  const int t = threadIdx.x;
  const int base = blockIdx.x * SCAN_CHUNK + t * 4;

  int s = 0;
#pragma unroll
  for (int j = 0; j < 4; ++j) {
    const int idx = base + j;
    if (idx < N_NODES) s += counts[(size_t)idx * CSTRIDE];
  }
  red[t] = s;
  __syncthreads();
#pragma unroll
  for (int off = 128; off > 0; off >>= 1) {
    if (t < off) red[t] += red[t + off];
    __syncthreads();
  }
  if (t == 0) bsums[blockIdx.x] = red[0];
}

// ---------------------------------------------------------------------------
// Scan phase 2: one tiny block exclusive-scans the 98 block sums in place.
// ---------------------------------------------------------------------------
__global__ __launch_bounds__(128) void scan2_kernel(int* __restrict__ bsums) {
  __shared__ int ps[128];
  const int t = threadIdx.x;
  int v = (t < SCAN_BLOCKS) ? bsums[t] : 0;
  ps[t] = v;
  __syncthreads();
#pragma unroll
  for (int off = 1; off < 128; off <<= 1) {
    const int u = (t >= off) ? ps[t - off] : 0;
    __syncthreads();
    ps[t] += u;
    __syncthreads();
  }
  if (t < SCAN_BLOCKS) bsums[t] = (t == 0) ? 0 : ps[t - 1];
}

// ---------------------------------------------------------------------------
// Scan phase 3: block-local exclusive scan + block offset -> row_start.
// ---------------------------------------------------------------------------
__global__ __launch_bounds__(256) void scan3_kernel(
    const int* __restrict__ counts,
    const int* __restrict__ bsums,
    int* __restrict__ row_start) {
  __shared__ int ts[256];
  const int t = threadIdx.x;
  const int base = blockIdx.x * SCAN_CHUNK + t * 4;

  int c[4];
  int s = 0;
#pragma unroll
  for (int j = 0; j < 4; ++j) {
    const int idx = base + j;
    c[j] = (idx < N_NODES) ? counts[(size_t)idx * CSTRIDE] : 0;
    s += c[j];
  }
  ts[t] = s;
  __syncthreads();
#pragma unroll
  for (int off = 1; off < 256; off <<= 1) {
    const int u = (t >= off) ? ts[t - off] : 0;
    __syncthreads();
    ts[t] += u;
    __syncthreads();
  }

  if (base < N_NODES) {  // N_NODES % 4 == 0 -> full int4 in range
    int run = bsums[blockIdx.x] + ((t == 0) ? 0 : ts[t - 1]);
    int4 rs;
    rs.x = run; run += c[0];
    rs.y = run; run += c[1];
    rs.z = run; run += c[2];
    rs.w = run; run += c[3];
    ((int4*)row_start)[base >> 2] = rs;
  }
  if (blockIdx.x == 0 && t == 0) row_start[N_NODES] = N_EDGES;
}

// ---------------------------------------------------------------------------
// Kernel 4: atomic-free scatter. pos = row_start[row] + rank.
// ---------------------------------------------------------------------------
__global__ __launch_bounds__(256) void scatter_rank_kernel(
    const int* __restrict__ erows,
    const int* __restrict__ ecols,
    const float* __restrict__ evals,
    const ushort* __restrict__ rank,
    const int* __restrict__ row_start,
    int2* __restrict__ sorted) {
  const int i = blockIdx.x * blockDim.x + threadIdx.x;  // int4 group
  if (i * 4 >= N_EDGES) return;
  const int4 r = ((const int4*)erows)[i];
  const int4 c = ((const int4*)ecols)[i];
  const float4 v = ((const float4*)evals)[i];
  const ushort4 rk = ((const ushort4*)rank)[i];

  const int p0 = row_start[r.x] + rk.x;
  const int p1 = row_start[r.y] + rk.y;
  const int p2 = row_start[r.z] + rk.z;
  const int p3 = row_start[r.w] + rk.w;

  int2 s0; s0.x = c.x; s0.y = __float_as_int(v.x);
  int2 s1; s1.x = c.y; s1.y = __float_as_int(v.y);
  int2 s2; s2.x = c.z; s2.y = __float_as_int(v.z);
  int2 s3; s3.x = c.w; s3.y = __float_as_int(v.w);
  sorted[p0] = s0;
  sorted[p1] = s1;
  sorted[p2] = s2;
  sorted[p3] = s3;
}

// ---------------------------------------------------------------------------
// Kernel 5: CSR SpMM + fused ReLU. One 32-lane group per output row;
// bf16 h gather (8B/lane/edge), 4-edge unroll for load ILP.
// ---------------------------------------------------------------------------
__global__ __launch_bounds__(256) void spmm_csr_kernel(
    const int* __restrict__ row_start,
    const int2* __restrict__ sorted,
    const ushort* __restrict__ h,
    float* __restrict__ out) {
  const int tid = threadIdx.x;
  const int row = blockIdx.x * 8 + (tid >> 5);
  if (row >= N_NODES) return;

  const int beg = row_start[row];
  const int end = row_start[row + 1];
  const int j = (tid & 31) * 4;

  float a0 = 0.f, a1 = 0.f, a2 = 0.f, a3 = 0.f;

  int e = beg;
  for (; e + 3 < end; e += 4) {
    const int2 p0 = sorted[e];
    const int2 p1 = sorted[e + 1];
    const int2 p2 = sorted[e + 2];
    const int2 p3 = sorted[e + 3];
    const ushort4 q0 = *(const ushort4*)(h + (size_t)p0.x * FT + j);
    const ushort4 q1 = *(const ushort4*)(h + (size_t)p1.x * FT + j);
    const ushort4 q2 = *(const ushort4*)(h + (size_t)p2.x * FT + j);
    const ushort4 q3 = *(const ushort4*)(h + (size_t)p3.x * FT + j);
    const float v0 = __int_as_float(p0.y);
    const float v1 = __int_as_float(p1.y);
    const float v2 = __int_as_float(p2.y);
    const float v3 = __int_as_float(p3.y);
    a0 = fmaf(v0, bf2f(q0.x), a0);
    a1 = fmaf(v0, bf2f(q0.y), a1);
    a2 = fmaf(v0, bf2f(q0.z), a2);
    a3 = fmaf(v0, bf2f(q0.w), a3);
    a0 = fmaf(v1, bf2f(q1.x), a0);
    a1 = fmaf(v1, bf2f(q1.y), a1);
    a2 = fmaf(v1, bf2f(q1.z), a2);
    a3 = fmaf(v1, bf2f(q1.w), a3);
    a0 = fmaf(v2, bf2f(q2.x), a0);
    a1 = fmaf(v2, bf2f(q2.y), a1);
    a2 = fmaf(v2, bf2f(q2.z), a2);
    a3 = fmaf(v2, bf2f(q2.w), a3);
    a0 = fmaf(v3, bf2f(q3.x), a0);
    a1 = fmaf(v3, bf2f(q3.y), a1);
    a2 = fmaf(v3, bf2f(q3.z), a2);
    a3 = fmaf(v3, bf2f(q3.w), a3);
  }
  for (; e < end; ++e) {
    const int2 p0 = sorted[e];
    const float v0 = __int_as_float(p0.y);
    const ushort4 q0 = *(const ushort4*)(h + (size_t)p0.x * FT + j);
    a0 = fmaf(v0, bf2f(q0.x), a0);
    a1 = fmaf(v0, bf2f(q0.y), a1);
    a2 = fmaf(v0, bf2f(q0.z), a2);
    a3 = fmaf(v0, bf2f(q0.w), a3);
  }

  float4 r;
  r.x = fmaxf(a0, 0.f);
  r.y = fmaxf(a1, 0.f);
  r.z = fmaxf(a2, 0.f);
  r.w = fmaxf(a3, 0.f);
  *(float4*)(out + (size_t)row * FT + j) = r;
}

// ---------------------------------------------------------------------------
// Fallback (small ws): atomic scatter + relu on bf16 h.
// ---------------------------------------------------------------------------
__global__ __launch_bounds__(256) void edge_scatter_kernel(
    const int* __restrict__ erows,
    const int* __restrict__ ecols,
    const float* __restrict__ evals,
    const ushort* __restrict__ h,
    float* out) {
  const int tid = threadIdx.x;
  const int e = blockIdx.x * 8 + (tid >> 5);
  if (e >= N_EDGES) return;
  const int r = erows[e];
  const int c = ecols[e];
  const float v = evals[e];
  const int j = (tid & 31) * 4;
  const ushort4 q = *(const ushort4*)(h + (size_t)c * FT + j);
  float* op = out + (size_t)r * FT + j;
  atomicAdd(op + 0, v * bf2f(q.x));
  atomicAdd(op + 1, v * bf2f(q.y));
  atomicAdd(op + 2, v * bf2f(q.z));
  atomicAdd(op + 3, v * bf2f(q.w));
}

__global__ __launch_bounds__(256) void relu_kernel(float* out, int n4) {
  const int i = blockIdx.x * blockDim.x + threadIdx.x;
  if (i < n4) {
    float4 v = ((float4*)out)[i];
    v.x = fmaxf(v.x, 0.f);
    v.y = fmaxf(v.y, 0.f);
    v.z = fmaxf(v.z, 0.f);
    v.w = fmaxf(v.w, 0.f);
    ((float4*)out)[i] = v;
  }
}

extern "C" void kernel_launch(void* const* d_in, const int* in_sizes, int n_in,
                              void* d_out, int out_size, void* d_ws, size_t ws_size,
                              hipStream_t stream) {
  const float* x = (const float*)d_in[0];
  const int* erows = (const int*)d_in[1];
  const int* ecols = (const int*)d_in[2];
  const float* evals = (const float*)d_in[3];
  const float* W = (const float*)d_in[4];
  const float* b = (const float*)d_in[5];
  float* out = (float*)d_out;

  char* ws = (char*)d_ws;
  ushort* h = (ushort*)(ws + OFF_H);

  gemm_bias_kernel<<<(N_NODES + 255) / 256, 256, 0, stream>>>(x, W, b, h);

  if (ws_size >= (size_t)WS_NEEDED) {
    int* row_start = (int*)(ws + OFF_ROWSTART);
    int* counts = (int*)(ws + OFF_COUNTS);
    int2* sorted = (int2*)(ws + OFF_SORTED);
    ushort* rank = (ushort*)(ws + OFF_RANK);
    int* bsums = (int*)(ws + OFF_BSUMS);

    hipMemsetAsync(counts, 0, (size_t)N_NODES * CSTRIDE * sizeof(int), stream);
    hist_rank_kernel<<<(N_EDGES / 4 + 255) / 256, 256, 0, stream>>>(
        erows, counts, rank);
    scan1_kernel<<<SCAN_BLOCKS, 256, 0, stream>>>(counts, bsums);
    scan2_kernel<<<1, 128, 0, stream>>>(bsums);
    scan3_kernel<<<SCAN_BLOCKS, 256, 0, stream>>>(counts, bsums, row_start);
    scatter_rank_kernel<<<(N_EDGES / 4 + 255) / 256, 256, 0, stream>>>(
        erows, ecols, evals, rank, row_start, sorted);
    spmm_csr_kernel<<<(N_NODES + 7) / 8, 256, 0, stream>>>(row_start, sorted,
                                                           h, out);
  } else {
    hipMemsetAsync(d_out, 0, (size_t)out_size * sizeof(float), stream);
    edge_scatter_kernel<<<(N_EDGES + 7) / 8, 256, 0, stream>>>(erows, ecols,
                                                               evals, h, out);
    const int n4 = out_size / 4;
    relu_kernel<<<(n4 + 255) / 256, 256, 0, stream>>>(out, n4);
  }
}